// Round 2
// 543.306 us; speedup vs baseline: 1.0212x; 1.0212x over previous
//
#include <hip/hip_runtime.h>

// Problem constants (from reference setup_inputs)
constexpr int BN = 24;   // batch*num_cams
constexpr int C  = 256;  // channels
constexpr int IH = 16;   // input H
constexpr int IW = 44;   // input W
constexpr int OH = 128;  // output H
constexpr int OW = 128;  // output W

// Native vector type for nontemporal builtin (HIP_vector_type<float,4> is a
// class and is rejected by __builtin_nontemporal_store; this ext_vector_type
// is layout-identical).
typedef float floatx4 __attribute__((ext_vector_type(4)));

// Mathematical identity: einsum('nchw,ndhw->nchw', img, softmax(logits, d))
//   = img * sum_d softmax = img. So the kernel is purely the bilinear
// upsample of img_feat; depth_logits never needs to be read.
//
// Half-pixel-center bilinear (align_corners=False), clamp-to-edge.
//
// Layout: each wave owns a contiguous 256-float4 (4 KB) tile of the output
// (= 8 full output rows of one (n,c) plane; nc is constant per tile since
// 4096 float4 per plane is a multiple of 256). Each thread produces 4
// float4 at tile offsets lane + q*64, so every store instruction is a
// fully coalesced 1 KB wave-wide write. x4 = (lane&31)*4 is q-invariant,
// so horizontal coefficients are computed ONCE per thread and reused for
// all 4 output quads; only the cheap vertical coefficients vary (y steps
// by 2 per q). Nontemporal stores keep the 402 MB output stream from
// evicting the ~18 MB input working set in L2.
__global__ __launch_bounds__(256) void lss_bilinear_kernel(
    const float* __restrict__ in, float* __restrict__ out) {
    const int t    = blockIdx.x * blockDim.x + threadIdx.x;
    const int lane = t & 63;
    const int wbase = (t >> 6) << 8;        // first float4 index of wave tile
    const int nc    = wbase >> 12;          // plane id, constant per tile
    const int x4    = (lane & 31) << 2;     // 0..124 step 4
    const int ybase = ((wbase >> 5) & (OH - 1)) + (lane >> 5);  // y for q=0

    const float* __restrict__ plane = in + (size_t)nc * (IH * IW);

    // ---- horizontal coefficients: computed once, reused across q ----
    int   x0[4], x1[4];
    float wx[4];
#pragma unroll
    for (int j = 0; j < 4; ++j) {
        const int x = x4 + j;
        // xs = (x+0.5)*(44/128) - 0.5 = 0.34375*x - 0.328125
        const float xs = fmaf((float)x, 0.34375f, -0.328125f);
        const float xf = floorf(xs);
        wx[j] = xs - xf;
        int a = (int)xf;
        int b = a + 1;
        x0[j] = min(max(a, 0), IW - 1);
        x1[j] = min(max(b, 0), IW - 1);
    }

    floatx4* __restrict__ outp = reinterpret_cast<floatx4*>(out) + wbase + lane;

#pragma unroll
    for (int q = 0; q < 4; ++q) {
        const int y = ybase + q * 2;
        // ys = (y+0.5)*(16/128) - 0.5 = 0.125*y - 0.4375
        const float ys = fmaf((float)y, 0.125f, -0.4375f);
        const float yf = floorf(ys);
        const float wy = ys - yf;
        int ya = (int)yf;
        int yb = ya + 1;
        ya = min(max(ya, 0), IH - 1);
        yb = min(max(yb, 0), IH - 1);

        const float* __restrict__ row0 = plane + ya * IW;
        const float* __restrict__ row1 = plane + yb * IW;

        floatx4 o;
#pragma unroll
        for (int j = 0; j < 4; ++j) {
            const float v00 = row0[x0[j]];
            const float v01 = row0[x1[j]];
            const float v10 = row1[x0[j]];
            const float v11 = row1[x1[j]];
            const float top = fmaf(v01 - v00, wx[j], v00);
            const float bot = fmaf(v11 - v10, wx[j], v10);
            o[j] = fmaf(bot - top, wy, top);
        }
        __builtin_nontemporal_store(o, outp + q * 64);
    }
}

extern "C" void kernel_launch(void* const* d_in, const int* in_sizes, int n_in,
                              void* d_out, int out_size, void* d_ws, size_t ws_size,
                              hipStream_t stream) {
    const float* img_feat = (const float*)d_in[0];
    // d_in[1] (depth_logits) is mathematically a no-op: softmax sums to 1
    // over the reduced axis -> einsum result == img_feat.
    float* out = (float*)d_out;

    constexpr int total_f4 = BN * C * OH * OW / 4;   // 25,165,824
    constexpr int f4_per_thread = 4;
    constexpr int block = 256;
    constexpr int grid = total_f4 / (block * f4_per_thread);  // 24,576 (exact)
    lss_bilinear_kernel<<<grid, block, 0, stream>>>(img_feat, out);
}